// Round 1
// baseline (293.550 us; speedup 1.0000x reference)
//
#include <hip/hip_runtime.h>
#include <hip/hip_bf16.h>

// Problem: b=16, W=512, H=512, E=64, fp32 in.
// out: 16x2 coords (written as float) then 16 max vals (float). 48 floats.

#define B 16
#define W 512
#define H 512
#define E 64
#define NPIX ((size_t)B * W * H)
#define PIX_PER_B (W * H)
#define ROWS 16           // output rows per score block
#define NSTRIPS (W / ROWS)
#define EPS 1e-8f

// ---------- K0: normalize queries ----------
__global__ void qnorm_kernel(const float* __restrict__ qf, float* __restrict__ qn) {
    int b = blockIdx.x;
    int e = threadIdx.x;          // 64 threads
    float q = qf[b * E + e];
    float s = q * q;
    #pragma unroll
    for (int off = 32; off; off >>= 1) s += __shfl_xor(s, off, 64);
    qn[b * E + e] = q * rsqrtf(s + EPS);
}

// ---------- K1: cosine value map ----------
// 16 lanes per pixel, each lane loads float4 (16B). Block of 256 threads
// reads a contiguous 4 KiB chunk (16 pixels x 256 B).
__global__ __launch_bounds__(256) void vmap_kernel(const float* __restrict__ mf,
                                                   const float* __restrict__ qn,
                                                   float* __restrict__ vmap) {
    __shared__ float q[E];
    size_t p0 = (size_t)blockIdx.x * 16;         // first pixel of this block
    int b = (int)(p0 >> 18);                     // / (512*512); block never crosses batch
    if (threadIdx.x < E) q[threadIdx.x] = qn[b * E + threadIdx.x];
    __syncthreads();

    int t = threadIdx.x;
    size_t p = p0 + (t >> 4);                    // pixel for this 16-lane group
    int j = t & 15;                              // lane within pixel
    const float4 m4 = *reinterpret_cast<const float4*>(mf + p * E + j * 4);
    const float4 q4 = *reinterpret_cast<const float4*>(&q[j * 4]);

    float dot = m4.x * q4.x + m4.y * q4.y + m4.z * q4.z + m4.w * q4.w;
    float sq  = m4.x * m4.x + m4.y * m4.y + m4.z * m4.z + m4.w * m4.w;
    #pragma unroll
    for (int off = 8; off; off >>= 1) {
        dot += __shfl_xor(dot, off, 16);
        sq  += __shfl_xor(sq,  off, 16);
    }
    if (j == 0) vmap[p] = dot * rsqrtf(sq + EPS);
}

// ---------- K2: 5x5 window sum + per-strip argmax ----------
// Block = 256 threads handles one (batch, 16-row strip). Horizontal 5-tap
// sums staged in LDS (with 2-row halo), then vertical 5-tap + argmax.
__global__ __launch_bounds__(256) void score_kernel(const float* __restrict__ vmap,
                                                    float* __restrict__ pval,
                                                    int* __restrict__ pidx) {
    int strip = blockIdx.x;
    int b = blockIdx.y;
    int x0 = strip * ROWS;
    const float* v = vmap + (size_t)b * PIX_PER_B;
    int t = threadIdx.x;

    __shared__ float hs[ROWS + 4][H];   // 20 x 512 x 4B = 40 KiB
    for (int r = 0; r < ROWS + 4; ++r) {
        int gr = x0 - 2 + r;
        #pragma unroll
        for (int c = 0; c < 2; ++c) {
            int y = t * 2 + c;
            float s = 0.f;
            if (gr >= 0 && gr < W) {
                const float* row = v + gr * H;
                #pragma unroll
                for (int dy = -2; dy <= 2; ++dy) {
                    int yy = y + dy;
                    if (yy >= 0 && yy < H) s += row[yy];
                }
            }
            hs[r][y] = s;
        }
    }
    __syncthreads();

    float best = -1e30f;
    int bidx = 0;
    for (int x = 0; x < ROWS; ++x) {
        #pragma unroll
        for (int c = 0; c < 2; ++c) {
            int y = t * 2 + c;
            float s = hs[x][y] + hs[x + 1][y] + hs[x + 2][y] + hs[x + 3][y] + hs[x + 4][y];
            int idx = (x0 + x) * H + y;
            if (s > best || (s == best && idx < bidx)) { best = s; bidx = idx; }
        }
    }

    __shared__ float rv[256];
    __shared__ int   ri[256];
    rv[t] = best; ri[t] = bidx;
    __syncthreads();
    for (int off = 128; off; off >>= 1) {
        if (t < off) {
            float ov = rv[t + off]; int oi = ri[t + off];
            if (ov > rv[t] || (ov == rv[t] && oi < ri[t])) { rv[t] = ov; ri[t] = oi; }
        }
        __syncthreads();
    }
    if (t == 0) {
        pval[b * NSTRIPS + strip] = rv[0];
        pidx[b * NSTRIPS + strip] = ri[0];
    }
}

// ---------- K3: final per-batch reduce + output ----------
__global__ void final_kernel(const float* __restrict__ pval,
                             const int* __restrict__ pidx,
                             float* __restrict__ out) {
    int b = blockIdx.x;
    int t = threadIdx.x;  // 64 threads, first NSTRIPS valid
    float v = -1e30f;
    int idx = 0x7fffffff;
    if (t < NSTRIPS) { v = pval[b * NSTRIPS + t]; idx = pidx[b * NSTRIPS + t]; }
    #pragma unroll
    for (int off = 32; off; off >>= 1) {
        float ov = __shfl_xor(v, off, 64);
        int oi = __shfl_xor(idx, off, 64);
        if (ov > v || (ov == v && oi < idx)) { v = ov; idx = oi; }
    }
    if (t == 0) {
        out[b * 2 + 0] = (float)(idx >> 9);    // xs = flat // H
        out[b * 2 + 1] = (float)(idx & (H-1)); // ys = flat % H
        out[2 * B + b] = v;                    // max_vals after the 32 coord floats
    }
}

extern "C" void kernel_launch(void* const* d_in, const int* in_sizes, int n_in,
                              void* d_out, int out_size, void* d_ws, size_t ws_size,
                              hipStream_t stream) {
    const float* mf = (const float*)d_in[0];   // (16,512,512,64)
    const float* qf = (const float*)d_in[1];   // (16,64)
    float* out = (float*)d_out;                // 48 floats

    // workspace layout (all 4 KiB aligned)
    char* ws = (char*)d_ws;
    float* qn   = (float*)(ws);                         // 16*64 floats   (4 KiB)
    float* vmap = (float*)(ws + 4096);                  // 16*512*512 f   (16 MiB)
    char* after = ws + 4096 + (size_t)NPIX * 4;
    float* pval = (float*)after;                        // 512 floats
    int*   pidx = (int*)(after + 4096);                 // 512 ints

    qnorm_kernel<<<B, 64, 0, stream>>>(qf, qn);
    vmap_kernel<<<(int)(NPIX / 16), 256, 0, stream>>>(mf, qn, vmap);
    dim3 sgrid(NSTRIPS, B);
    score_kernel<<<sgrid, 256, 0, stream>>>(vmap, pval, pidx);
    final_kernel<<<B, 64, 0, stream>>>(pval, pidx, out);
}

// Round 2
// 253.811 us; speedup vs baseline: 1.1566x; 1.1566x over previous
//
#include <hip/hip_runtime.h>
#include <hip/hip_bf16.h>

// Problem: b=16, W=512, H=512, E=64, fp32 in.
// out: 16x2 coords (written as float) then 16 max vals (float). 48 floats.

#define B 16
#define W 512
#define H 512
#define E 64
#define NPIX ((size_t)B * W * H)
#define PIX_PER_B (W * H)
#define ROWS 16           // output rows per score block
#define NSTRIPS (W / ROWS)
#define EPS 1e-8f
#define GX 128            // blocks per batch for vmap (persistent grid-stride)

// ---------- K1: cosine value map (persistent, grid-stride) ----------
// Block = 256 threads = 16 groups of 16 lanes; each group owns one pixel per
// iteration, lane j loads float4 of embedding elems [4j..4j+3]. A wave reads
// 1 KB contiguous per pixel-quad. Query normalized in-register once per block
// (no LDS, no syncthreads). 128 blocks/batch x 128 iterations, 2x unrolled.
__global__ __launch_bounds__(256) void vmap_kernel(const float* __restrict__ mf,
                                                   const float* __restrict__ qf,
                                                   float* __restrict__ vmap) {
    const int b = blockIdx.y;
    const int t = threadIdx.x;
    const int j = t & 15;

    // load + normalize query fragment (identical in every 16-lane group)
    float4 q4 = *reinterpret_cast<const float4*>(qf + b * E + j * 4);
    float qs = q4.x * q4.x + q4.y * q4.y + q4.z * q4.z + q4.w * q4.w;
    #pragma unroll
    for (int off = 8; off; off >>= 1) qs += __shfl_xor(qs, off, 16);
    const float qinv = rsqrtf(qs + EPS);
    q4.x *= qinv; q4.y *= qinv; q4.z *= qinv; q4.w *= qinv;

    const float* mfb = mf + (size_t)b * PIX_PER_B * E;
    float* vb = vmap + (size_t)b * PIX_PER_B;

    const int pstep = GX * 16;                     // pixels covered per grid-iter
    int p0 = blockIdx.x * 16 + (t >> 4);
    // PIX_PER_B / pstep = 128 iterations exactly; unroll 2 -> 64
    #pragma unroll 1
    for (int it = 0; it < PIX_PER_B / (2 * pstep); ++it) {
        const int pa = p0;
        const int pb = p0 + pstep;
        const float4 ma = *reinterpret_cast<const float4*>(mfb + (size_t)pa * E + j * 4);
        const float4 mb = *reinterpret_cast<const float4*>(mfb + (size_t)pb * E + j * 4);

        float da = ma.x * q4.x + ma.y * q4.y + ma.z * q4.z + ma.w * q4.w;
        float sa = ma.x * ma.x + ma.y * ma.y + ma.z * ma.z + ma.w * ma.w;
        float db = mb.x * q4.x + mb.y * q4.y + mb.z * q4.z + mb.w * q4.w;
        float sb = mb.x * mb.x + mb.y * mb.y + mb.z * mb.z + mb.w * mb.w;
        #pragma unroll
        for (int off = 8; off; off >>= 1) {
            da += __shfl_xor(da, off, 16);
            sa += __shfl_xor(sa, off, 16);
            db += __shfl_xor(db, off, 16);
            sb += __shfl_xor(sb, off, 16);
        }
        if (j == 0) {
            vb[pa] = da * rsqrtf(sa + EPS);
            vb[pb] = db * rsqrtf(sb + EPS);
        }
        p0 += 2 * pstep;
    }
}

// ---------- K2: 5x5 window sum + per-strip argmax ----------
__global__ __launch_bounds__(256) void score_kernel(const float* __restrict__ vmap,
                                                    float* __restrict__ pval,
                                                    int* __restrict__ pidx) {
    int strip = blockIdx.x;
    int b = blockIdx.y;
    int x0 = strip * ROWS;
    const float* v = vmap + (size_t)b * PIX_PER_B;
    int t = threadIdx.x;

    __shared__ float hs[ROWS + 4][H];   // 20 x 512 x 4B = 40 KiB
    for (int r = 0; r < ROWS + 4; ++r) {
        int gr = x0 - 2 + r;
        #pragma unroll
        for (int c = 0; c < 2; ++c) {
            int y = t * 2 + c;
            float s = 0.f;
            if (gr >= 0 && gr < W) {
                const float* row = v + gr * H;
                #pragma unroll
                for (int dy = -2; dy <= 2; ++dy) {
                    int yy = y + dy;
                    if (yy >= 0 && yy < H) s += row[yy];
                }
            }
            hs[r][y] = s;
        }
    }
    __syncthreads();

    float best = -1e30f;
    int bidx = 0;
    for (int x = 0; x < ROWS; ++x) {
        #pragma unroll
        for (int c = 0; c < 2; ++c) {
            int y = t * 2 + c;
            float s = hs[x][y] + hs[x + 1][y] + hs[x + 2][y] + hs[x + 3][y] + hs[x + 4][y];
            int idx = (x0 + x) * H + y;
            if (s > best || (s == best && idx < bidx)) { best = s; bidx = idx; }
        }
    }

    __shared__ float rv[256];
    __shared__ int   ri[256];
    rv[t] = best; ri[t] = bidx;
    __syncthreads();
    for (int off = 128; off; off >>= 1) {
        if (t < off) {
            float ov = rv[t + off]; int oi = ri[t + off];
            if (ov > rv[t] || (ov == rv[t] && oi < ri[t])) { rv[t] = ov; ri[t] = oi; }
        }
        __syncthreads();
    }
    if (t == 0) {
        pval[b * NSTRIPS + strip] = rv[0];
        pidx[b * NSTRIPS + strip] = ri[0];
    }
}

// ---------- K3: final per-batch reduce + output ----------
__global__ void final_kernel(const float* __restrict__ pval,
                             const int* __restrict__ pidx,
                             float* __restrict__ out) {
    int b = blockIdx.x;
    int t = threadIdx.x;  // 64 threads, first NSTRIPS valid
    float v = -1e30f;
    int idx = 0x7fffffff;
    if (t < NSTRIPS) { v = pval[b * NSTRIPS + t]; idx = pidx[b * NSTRIPS + t]; }
    #pragma unroll
    for (int off = 32; off; off >>= 1) {
        float ov = __shfl_xor(v, off, 64);
        int oi = __shfl_xor(idx, off, 64);
        if (ov > v || (ov == v && oi < idx)) { v = ov; idx = oi; }
    }
    if (t == 0) {
        out[b * 2 + 0] = (float)(idx >> 9);    // xs = flat // H
        out[b * 2 + 1] = (float)(idx & (H-1)); // ys = flat % H
        out[2 * B + b] = v;                    // max_vals after the 32 coord floats
    }
}

extern "C" void kernel_launch(void* const* d_in, const int* in_sizes, int n_in,
                              void* d_out, int out_size, void* d_ws, size_t ws_size,
                              hipStream_t stream) {
    const float* mf = (const float*)d_in[0];   // (16,512,512,64)
    const float* qf = (const float*)d_in[1];   // (16,64)
    float* out = (float*)d_out;                // 48 floats

    char* ws = (char*)d_ws;
    float* vmap = (float*)ws;                           // 16*512*512 f (16 MiB)
    char* after = ws + (size_t)NPIX * 4;
    float* pval = (float*)after;                        // 512 floats
    int*   pidx = (int*)(after + 4096);                 // 512 ints

    dim3 vgrid(GX, B);
    vmap_kernel<<<vgrid, 256, 0, stream>>>(mf, qf, vmap);
    dim3 sgrid(NSTRIPS, B);
    score_kernel<<<sgrid, 256, 0, stream>>>(vmap, pval, pidx);
    final_kernel<<<B, 64, 0, stream>>>(pval, pidx, out);
}

// Round 3
// 235.933 us; speedup vs baseline: 1.2442x; 1.0758x over previous
//
#include <hip/hip_runtime.h>
#include <hip/hip_bf16.h>

// Problem: b=16, W=512, H=512, E=64, fp32 in.
// out: 16x2 coords (written as float) then 16 max vals (float). 48 floats.

#define B 16
#define W 512
#define H 512
#define E 64
#define NPIX ((size_t)B * W * H)
#define PIX_PER_B (W * H)
#define SROWS 16          // output rows per score block
#define NSTRIPS (W / SROWS)
#define EPS 1e-8f
#define GX 128            // blocks per batch for vmap

// ---------- K1: cosine value map (persistent, grid-stride, 4x unrolled) ----------
// 16 lanes per pixel; lane j loads float4 of embedding elems [4j..4j+3].
// 4 pixels per group-iteration -> 4 KB of loads in flight per wave.
__global__ __launch_bounds__(256) void vmap_kernel(const float* __restrict__ mf,
                                                   const float* __restrict__ qf,
                                                   float* __restrict__ vmap) {
    const int b = blockIdx.y;
    const int t = threadIdx.x;
    const int j = t & 15;

    float4 q4 = *reinterpret_cast<const float4*>(qf + b * E + j * 4);
    float qs = q4.x * q4.x + q4.y * q4.y + q4.z * q4.z + q4.w * q4.w;
    #pragma unroll
    for (int off = 8; off; off >>= 1) qs += __shfl_xor(qs, off, 16);
    const float qinv = rsqrtf(qs + EPS);
    q4.x *= qinv; q4.y *= qinv; q4.z *= qinv; q4.w *= qinv;

    const float* mfb = mf + (size_t)b * PIX_PER_B * E;
    float* vb = vmap + (size_t)b * PIX_PER_B;

    const int pstep = GX * 16;                     // 2048 pixels
    int p = blockIdx.x * 16 + (t >> 4);

    #pragma unroll 1
    for (int it = 0; it < PIX_PER_B / (4 * pstep); ++it) {   // 32 iterations
        const float4 m0 = *reinterpret_cast<const float4*>(mfb + (size_t)(p            ) * E + j * 4);
        const float4 m1 = *reinterpret_cast<const float4*>(mfb + (size_t)(p +     pstep) * E + j * 4);
        const float4 m2 = *reinterpret_cast<const float4*>(mfb + (size_t)(p + 2 * pstep) * E + j * 4);
        const float4 m3 = *reinterpret_cast<const float4*>(mfb + (size_t)(p + 3 * pstep) * E + j * 4);

        float d0 = m0.x*q4.x + m0.y*q4.y + m0.z*q4.z + m0.w*q4.w;
        float s0 = m0.x*m0.x + m0.y*m0.y + m0.z*m0.z + m0.w*m0.w;
        float d1 = m1.x*q4.x + m1.y*q4.y + m1.z*q4.z + m1.w*q4.w;
        float s1 = m1.x*m1.x + m1.y*m1.y + m1.z*m1.z + m1.w*m1.w;
        float d2 = m2.x*q4.x + m2.y*q4.y + m2.z*q4.z + m2.w*q4.w;
        float s2 = m2.x*m2.x + m2.y*m2.y + m2.z*m2.z + m2.w*m2.w;
        float d3 = m3.x*q4.x + m3.y*q4.y + m3.z*q4.z + m3.w*q4.w;
        float s3 = m3.x*m3.x + m3.y*m3.y + m3.z*m3.z + m3.w*m3.w;

        #pragma unroll
        for (int off = 8; off; off >>= 1) {
            d0 += __shfl_xor(d0, off, 16);  s0 += __shfl_xor(s0, off, 16);
            d1 += __shfl_xor(d1, off, 16);  s1 += __shfl_xor(s1, off, 16);
            d2 += __shfl_xor(d2, off, 16);  s2 += __shfl_xor(s2, off, 16);
            d3 += __shfl_xor(d3, off, 16);  s3 += __shfl_xor(s3, off, 16);
        }
        if (j == 0) {
            vb[p            ] = d0 * rsqrtf(s0 + EPS);
            vb[p +     pstep] = d1 * rsqrtf(s1 + EPS);
            vb[p + 2 * pstep] = d2 * rsqrtf(s2 + EPS);
            vb[p + 3 * pstep] = d3 * rsqrtf(s3 + EPS);
        }
        p += 4 * pstep;
    }
}

// ---------- K2: 5x5 window sum + per-strip argmax (vertical-first separable) ----------
// Block = 256 threads, each owns columns y = t and t+256 of one (batch, 16-row
// strip). Stream 20 rows with a 5-deep register window (coalesced dword loads,
// prefetched 1 row ahead); write vertical sums to a double-buffered LDS row;
// horizontal 5-tap from consecutive (conflict-free) LDS reads; argmax.
__global__ __launch_bounds__(256) void score_kernel(const float* __restrict__ vmap,
                                                    float* __restrict__ pval,
                                                    int* __restrict__ pidx) {
    const int strip = blockIdx.x;
    const int b = blockIdx.y;
    const int x0 = strip * SROWS;
    const float* v = vmap + (size_t)b * PIX_PER_B;
    const int t = threadIdx.x;
    const int y0 = t, y1 = t + 256;

    __shared__ float vs[2][H + 4];       // 2 x 516 floats, halo 2 each side
    if (t < 2) {
        vs[0][t] = 0.f; vs[0][H + 2 + t] = 0.f;
        vs[1][t] = 0.f; vs[1][H + 2 + t] = 0.f;
    }
    __syncthreads();

    float w0a = 0, w1a = 0, w2a = 0, w3a = 0, w4a = 0;
    float w0b = 0, w1b = 0, w2b = 0, w3b = 0, w4b = 0;
    float best = -1e30f;
    int bidx = 0x7fffffff;

    // prefetch row r=0
    float a_next = 0.f, c_next = 0.f;
    {
        int gr = x0 - 2;
        if (gr >= 0) { a_next = v[gr * H + y0]; c_next = v[gr * H + y1]; }
    }

    #pragma unroll
    for (int r = 0; r < SROWS + 4; ++r) {
        float a = a_next, c = c_next;
        if (r < SROWS + 3) {                     // prefetch row r+1
            int gr = x0 - 1 + r;
            if (gr >= 0 && gr < W) {
                a_next = v[gr * H + y0];
                c_next = v[gr * H + y1];
            } else { a_next = 0.f; c_next = 0.f; }
        }
        w0a = w1a; w1a = w2a; w2a = w3a; w3a = w4a; w4a = a;
        w0b = w1b; w1b = w2b; w2b = w3b; w3b = w4b; w4b = c;

        if (r >= 4) {
            const int x = x0 + r - 4;
            const int buf = r & 1;
            vs[buf][2 + y0] = w0a + w1a + w2a + w3a + w4a;
            vs[buf][2 + y1] = w0b + w1b + w2b + w3b + w4b;
            __syncthreads();
            float sa = vs[buf][y0] + vs[buf][y0+1] + vs[buf][y0+2] + vs[buf][y0+3] + vs[buf][y0+4];
            float sb = vs[buf][y1] + vs[buf][y1+1] + vs[buf][y1+2] + vs[buf][y1+3] + vs[buf][y1+4];
            int ia = x * H + y0;
            int ib = x * H + y1;
            if (sa > best || (sa == best && ia < bidx)) { best = sa; bidx = ia; }
            if (sb > best || (sb == best && ib < bidx)) { best = sb; bidx = ib; }
        }
    }

    __shared__ float rv[256];
    __shared__ int   ri[256];
    rv[t] = best; ri[t] = bidx;
    __syncthreads();
    for (int off = 128; off; off >>= 1) {
        if (t < off) {
            float ov = rv[t + off]; int oi = ri[t + off];
            if (ov > rv[t] || (ov == rv[t] && oi < ri[t])) { rv[t] = ov; ri[t] = oi; }
        }
        __syncthreads();
    }
    if (t == 0) {
        pval[b * NSTRIPS + strip] = rv[0];
        pidx[b * NSTRIPS + strip] = ri[0];
    }
}

// ---------- K3: final per-batch reduce + output ----------
__global__ void final_kernel(const float* __restrict__ pval,
                             const int* __restrict__ pidx,
                             float* __restrict__ out) {
    int b = blockIdx.x;
    int t = threadIdx.x;  // 64 threads, first NSTRIPS valid
    float v = -1e30f;
    int idx = 0x7fffffff;
    if (t < NSTRIPS) { v = pval[b * NSTRIPS + t]; idx = pidx[b * NSTRIPS + t]; }
    #pragma unroll
    for (int off = 32; off; off >>= 1) {
        float ov = __shfl_xor(v, off, 64);
        int oi = __shfl_xor(idx, off, 64);
        if (ov > v || (ov == v && oi < idx)) { v = ov; idx = oi; }
    }
    if (t == 0) {
        out[b * 2 + 0] = (float)(idx >> 9);    // xs = flat // H
        out[b * 2 + 1] = (float)(idx & (H-1)); // ys = flat % H
        out[2 * B + b] = v;                    // max_vals after the 32 coord floats
    }
}

extern "C" void kernel_launch(void* const* d_in, const int* in_sizes, int n_in,
                              void* d_out, int out_size, void* d_ws, size_t ws_size,
                              hipStream_t stream) {
    const float* mf = (const float*)d_in[0];   // (16,512,512,64)
    const float* qf = (const float*)d_in[1];   // (16,64)
    float* out = (float*)d_out;                // 48 floats

    char* ws = (char*)d_ws;
    float* vmap = (float*)ws;                           // 16*512*512 f (16 MiB)
    char* after = ws + (size_t)NPIX * 4;
    float* pval = (float*)after;                        // 512 floats
    int*   pidx = (int*)(after + 4096);                 // 512 ints

    dim3 vgrid(GX, B);
    vmap_kernel<<<vgrid, 256, 0, stream>>>(mf, qf, vmap);
    dim3 sgrid(NSTRIPS, B);
    score_kernel<<<sgrid, 256, 0, stream>>>(vmap, pval, pidx);
    final_kernel<<<B, 64, 0, stream>>>(pval, pidx, out);
}

// Round 4
// 229.067 us; speedup vs baseline: 1.2815x; 1.0300x over previous
//
#include <hip/hip_runtime.h>
#include <hip/hip_bf16.h>

// Problem: b=16, W=512, H=512, E=64, fp32 in.
// out: 16x2 coords (written as float) then 16 max vals (float). 48 floats.

#define B 16
#define W 512
#define H 512
#define E 64
#define NPIX ((size_t)B * W * H)
#define PIX_PER_B (W * H)
#define SROWS 16          // output rows per score block
#define NSTRIPS (W / SROWS)
#define EPS 1e-8f
#define GX 128            // blocks per batch for vmap

// Sum across each 16-lane DPP row via row_shl cascade; result valid in lane 0
// of each row. VALU-only (no DS pipe), bound_ctrl=1 shifts zeros in from the
// row edge. row_shl:N = 0x100|N.
__device__ __forceinline__ float row16_sum(float x) {
    int s;
    s = __builtin_amdgcn_update_dpp(0, __float_as_int(x), 0x101, 0xf, 0xf, true);
    x += __int_as_float(s);
    s = __builtin_amdgcn_update_dpp(0, __float_as_int(x), 0x102, 0xf, 0xf, true);
    x += __int_as_float(s);
    s = __builtin_amdgcn_update_dpp(0, __float_as_int(x), 0x104, 0xf, 0xf, true);
    x += __int_as_float(s);
    s = __builtin_amdgcn_update_dpp(0, __float_as_int(x), 0x108, 0xf, 0xf, true);
    x += __int_as_float(s);
    return x;
}

// ---------- K1: cosine value map (persistent, grid-stride, 4x unrolled) ----------
// 16 lanes per pixel; lane j loads float4 of embedding elems [4j..4j+3].
// Reduction via DPP (VALU), zero DS-pipe traffic in the hot loop.
__global__ __launch_bounds__(256) void vmap_kernel(const float* __restrict__ mf,
                                                   const float* __restrict__ qf,
                                                   float* __restrict__ vmap) {
    const int b = blockIdx.y;
    const int t = threadIdx.x;
    const int j = t & 15;

    float4 q4 = *reinterpret_cast<const float4*>(qf + b * E + j * 4);
    float qs = q4.x * q4.x + q4.y * q4.y + q4.z * q4.z + q4.w * q4.w;
    #pragma unroll
    for (int off = 8; off; off >>= 1) qs += __shfl_xor(qs, off, 16);
    const float qinv = rsqrtf(qs + EPS);
    q4.x *= qinv; q4.y *= qinv; q4.z *= qinv; q4.w *= qinv;

    const float* mfb = mf + (size_t)b * PIX_PER_B * E;
    float* vb = vmap + (size_t)b * PIX_PER_B;

    const int pstep = GX * 16;                     // 2048 pixels
    int p = blockIdx.x * 16 + (t >> 4);

    #pragma unroll 1
    for (int it = 0; it < PIX_PER_B / (4 * pstep); ++it) {   // 32 iterations
        const float4 m0 = *reinterpret_cast<const float4*>(mfb + (size_t)(p            ) * E + j * 4);
        const float4 m1 = *reinterpret_cast<const float4*>(mfb + (size_t)(p +     pstep) * E + j * 4);
        const float4 m2 = *reinterpret_cast<const float4*>(mfb + (size_t)(p + 2 * pstep) * E + j * 4);
        const float4 m3 = *reinterpret_cast<const float4*>(mfb + (size_t)(p + 3 * pstep) * E + j * 4);

        float d0 = m0.x*q4.x + m0.y*q4.y + m0.z*q4.z + m0.w*q4.w;
        float s0 = m0.x*m0.x + m0.y*m0.y + m0.z*m0.z + m0.w*m0.w;
        float d1 = m1.x*q4.x + m1.y*q4.y + m1.z*q4.z + m1.w*q4.w;
        float s1 = m1.x*m1.x + m1.y*m1.y + m1.z*m1.z + m1.w*m1.w;
        float d2 = m2.x*q4.x + m2.y*q4.y + m2.z*q4.z + m2.w*q4.w;
        float s2 = m2.x*m2.x + m2.y*m2.y + m2.z*m2.z + m2.w*m2.w;
        float d3 = m3.x*q4.x + m3.y*q4.y + m3.z*q4.z + m3.w*q4.w;
        float s3 = m3.x*m3.x + m3.y*m3.y + m3.z*m3.z + m3.w*m3.w;

        d0 = row16_sum(d0);  s0 = row16_sum(s0);
        d1 = row16_sum(d1);  s1 = row16_sum(s1);
        d2 = row16_sum(d2);  s2 = row16_sum(s2);
        d3 = row16_sum(d3);  s3 = row16_sum(s3);

        if (j == 0) {
            vb[p            ] = d0 * rsqrtf(s0 + EPS);
            vb[p +     pstep] = d1 * rsqrtf(s1 + EPS);
            vb[p + 2 * pstep] = d2 * rsqrtf(s2 + EPS);
            vb[p + 3 * pstep] = d3 * rsqrtf(s3 + EPS);
        }
        p += 4 * pstep;
    }
}

// ---------- K2: 5x5 window sum + per-strip argmax (vertical-first separable) ----------
__global__ __launch_bounds__(256) void score_kernel(const float* __restrict__ vmap,
                                                    float* __restrict__ pval,
                                                    int* __restrict__ pidx) {
    const int strip = blockIdx.x;
    const int b = blockIdx.y;
    const int x0 = strip * SROWS;
    const float* v = vmap + (size_t)b * PIX_PER_B;
    const int t = threadIdx.x;
    const int y0 = t, y1 = t + 256;

    __shared__ float vs[2][H + 4];       // 2 x 516 floats, halo 2 each side
    if (t < 2) {
        vs[0][t] = 0.f; vs[0][H + 2 + t] = 0.f;
        vs[1][t] = 0.f; vs[1][H + 2 + t] = 0.f;
    }
    __syncthreads();

    float w0a = 0, w1a = 0, w2a = 0, w3a = 0, w4a = 0;
    float w0b = 0, w1b = 0, w2b = 0, w3b = 0, w4b = 0;
    float best = -1e30f;
    int bidx = 0x7fffffff;

    float a_next = 0.f, c_next = 0.f;
    {
        int gr = x0 - 2;
        if (gr >= 0) { a_next = v[gr * H + y0]; c_next = v[gr * H + y1]; }
    }

    #pragma unroll
    for (int r = 0; r < SROWS + 4; ++r) {
        float a = a_next, c = c_next;
        if (r < SROWS + 3) {                     // prefetch row r+1
            int gr = x0 - 1 + r;
            if (gr >= 0 && gr < W) {
                a_next = v[gr * H + y0];
                c_next = v[gr * H + y1];
            } else { a_next = 0.f; c_next = 0.f; }
        }
        w0a = w1a; w1a = w2a; w2a = w3a; w3a = w4a; w4a = a;
        w0b = w1b; w1b = w2b; w2b = w3b; w3b = w4b; w4b = c;

        if (r >= 4) {
            const int x = x0 + r - 4;
            const int buf = r & 1;
            vs[buf][2 + y0] = w0a + w1a + w2a + w3a + w4a;
            vs[buf][2 + y1] = w0b + w1b + w2b + w3b + w4b;
            __syncthreads();
            float sa = vs[buf][y0] + vs[buf][y0+1] + vs[buf][y0+2] + vs[buf][y0+3] + vs[buf][y0+4];
            float sb = vs[buf][y1] + vs[buf][y1+1] + vs[buf][y1+2] + vs[buf][y1+3] + vs[buf][y1+4];
            int ia = x * H + y0;
            int ib = x * H + y1;
            if (sa > best || (sa == best && ia < bidx)) { best = sa; bidx = ia; }
            if (sb > best || (sb == best && ib < bidx)) { best = sb; bidx = ib; }
        }
    }

    __shared__ float rv[256];
    __shared__ int   ri[256];
    rv[t] = best; ri[t] = bidx;
    __syncthreads();
    for (int off = 128; off; off >>= 1) {
        if (t < off) {
            float ov = rv[t + off]; int oi = ri[t + off];
            if (ov > rv[t] || (ov == rv[t] && oi < ri[t])) { rv[t] = ov; ri[t] = oi; }
        }
        __syncthreads();
    }
    if (t == 0) {
        pval[b * NSTRIPS + strip] = rv[0];
        pidx[b * NSTRIPS + strip] = ri[0];
    }
}

// ---------- K3: final per-batch reduce + output ----------
__global__ void final_kernel(const float* __restrict__ pval,
                             const int* __restrict__ pidx,
                             float* __restrict__ out) {
    int b = blockIdx.x;
    int t = threadIdx.x;  // 64 threads, first NSTRIPS valid
    float v = -1e30f;
    int idx = 0x7fffffff;
    if (t < NSTRIPS) { v = pval[b * NSTRIPS + t]; idx = pidx[b * NSTRIPS + t]; }
    #pragma unroll
    for (int off = 32; off; off >>= 1) {
        float ov = __shfl_xor(v, off, 64);
        int oi = __shfl_xor(idx, off, 64);
        if (ov > v || (ov == v && oi < idx)) { v = ov; idx = oi; }
    }
    if (t == 0) {
        out[b * 2 + 0] = (float)(idx >> 9);    // xs = flat // H
        out[b * 2 + 1] = (float)(idx & (H-1)); // ys = flat % H
        out[2 * B + b] = v;                    // max_vals after the 32 coord floats
    }
}

extern "C" void kernel_launch(void* const* d_in, const int* in_sizes, int n_in,
                              void* d_out, int out_size, void* d_ws, size_t ws_size,
                              hipStream_t stream) {
    const float* mf = (const float*)d_in[0];   // (16,512,512,64)
    const float* qf = (const float*)d_in[1];   // (16,64)
    float* out = (float*)d_out;                // 48 floats

    char* ws = (char*)d_ws;
    float* vmap = (float*)ws;                           // 16*512*512 f (16 MiB)
    char* after = ws + (size_t)NPIX * 4;
    float* pval = (float*)after;                        // 512 floats
    int*   pidx = (int*)(after + 4096);                 // 512 ints

    dim3 vgrid(GX, B);
    vmap_kernel<<<vgrid, 256, 0, stream>>>(mf, qf, vmap);
    dim3 sgrid(NSTRIPS, B);
    score_kernel<<<sgrid, 256, 0, stream>>>(vmap, pval, pidx);
    final_kernel<<<B, 64, 0, stream>>>(pval, pidx, out);
}

// Round 6
// 210.617 us; speedup vs baseline: 1.3938x; 1.0876x over previous
//
#include <hip/hip_runtime.h>
#include <hip/hip_bf16.h>

// Problem: b=16, W=512, H=512, E=64, fp32 in.
// out: 16x2 coords (written as float) then 16 max vals (float). 48 floats.

#define B 16
#define W 512
#define H 512
#define E 64
#define NPIX ((size_t)B * W * H)
#define PIX_PER_B (W * H)
#define SROWS 16          // output rows per score block
#define NSTRIPS (W / SROWS)
#define EPS 1e-8f
#define GX 128            // blocks per batch for vmap

// native clang vector type — __builtin_nontemporal_load requires this
// (HIP's float4 is a struct and is rejected)
typedef float floatx4 __attribute__((ext_vector_type(4)));

// Sum across each 16-lane DPP row via row_shl cascade; result valid in lane 0
// of each row. VALU-only (no DS pipe), bound_ctrl=1 shifts zeros in from the
// row edge. row_shl:N = 0x100|N.
__device__ __forceinline__ float row16_sum(float x) {
    int s;
    s = __builtin_amdgcn_update_dpp(0, __float_as_int(x), 0x101, 0xf, 0xf, true);
    x += __int_as_float(s);
    s = __builtin_amdgcn_update_dpp(0, __float_as_int(x), 0x102, 0xf, 0xf, true);
    x += __int_as_float(s);
    s = __builtin_amdgcn_update_dpp(0, __float_as_int(x), 0x104, 0xf, 0xf, true);
    x += __int_as_float(s);
    s = __builtin_amdgcn_update_dpp(0, __float_as_int(x), 0x108, 0xf, 0xf, true);
    x += __int_as_float(s);
    return x;
}

// ---------- K1: cosine value map (persistent, grid-stride, 4x unrolled) ----------
// 16 lanes per pixel; lane j loads 16B of embedding elems [4j..4j+3].
// mf is a use-once 1 GB stream -> nontemporal loads (no cache allocate).
__global__ __launch_bounds__(256) void vmap_kernel(const float* __restrict__ mf,
                                                   const float* __restrict__ qf,
                                                   float* __restrict__ vmap) {
    const int b = blockIdx.y;
    const int t = threadIdx.x;
    const int j = t & 15;

    floatx4 q4 = *reinterpret_cast<const floatx4*>(qf + b * E + j * 4);
    float qs = q4.x * q4.x + q4.y * q4.y + q4.z * q4.z + q4.w * q4.w;
    #pragma unroll
    for (int off = 8; off; off >>= 1) qs += __shfl_xor(qs, off, 16);
    const float qinv = rsqrtf(qs + EPS);
    q4 *= qinv;

    const float* mfb = mf + (size_t)b * PIX_PER_B * E;
    float* vb = vmap + (size_t)b * PIX_PER_B;

    const int pstep = GX * 16;                     // 2048 pixels
    int p = blockIdx.x * 16 + (t >> 4);

    #pragma unroll 1
    for (int it = 0; it < PIX_PER_B / (4 * pstep); ++it) {   // 32 iterations
        const floatx4 m0 = __builtin_nontemporal_load(
            reinterpret_cast<const floatx4*>(mfb + (size_t)(p            ) * E + j * 4));
        const floatx4 m1 = __builtin_nontemporal_load(
            reinterpret_cast<const floatx4*>(mfb + (size_t)(p +     pstep) * E + j * 4));
        const floatx4 m2 = __builtin_nontemporal_load(
            reinterpret_cast<const floatx4*>(mfb + (size_t)(p + 2 * pstep) * E + j * 4));
        const floatx4 m3 = __builtin_nontemporal_load(
            reinterpret_cast<const floatx4*>(mfb + (size_t)(p + 3 * pstep) * E + j * 4));

        float d0 = m0.x*q4.x + m0.y*q4.y + m0.z*q4.z + m0.w*q4.w;
        float s0 = m0.x*m0.x + m0.y*m0.y + m0.z*m0.z + m0.w*m0.w;
        float d1 = m1.x*q4.x + m1.y*q4.y + m1.z*q4.z + m1.w*q4.w;
        float s1 = m1.x*m1.x + m1.y*m1.y + m1.z*m1.z + m1.w*m1.w;
        float d2 = m2.x*q4.x + m2.y*q4.y + m2.z*q4.z + m2.w*q4.w;
        float s2 = m2.x*m2.x + m2.y*m2.y + m2.z*m2.z + m2.w*m2.w;
        float d3 = m3.x*q4.x + m3.y*q4.y + m3.z*q4.z + m3.w*q4.w;
        float s3 = m3.x*m3.x + m3.y*m3.y + m3.z*m3.z + m3.w*m3.w;

        d0 = row16_sum(d0);  s0 = row16_sum(s0);
        d1 = row16_sum(d1);  s1 = row16_sum(s1);
        d2 = row16_sum(d2);  s2 = row16_sum(s2);
        d3 = row16_sum(d3);  s3 = row16_sum(s3);

        if (j == 0) {
            vb[p            ] = d0 * rsqrtf(s0 + EPS);
            vb[p +     pstep] = d1 * rsqrtf(s1 + EPS);
            vb[p + 2 * pstep] = d2 * rsqrtf(s2 + EPS);
            vb[p + 3 * pstep] = d3 * rsqrtf(s3 + EPS);
        }
        p += 4 * pstep;
    }
}

// ---------- K2: 5x5 window sum + per-strip argmax (vertical-first separable) ----------
__global__ __launch_bounds__(256) void score_kernel(const float* __restrict__ vmap,
                                                    float* __restrict__ pval,
                                                    int* __restrict__ pidx) {
    const int strip = blockIdx.x;
    const int b = blockIdx.y;
    const int x0 = strip * SROWS;
    const float* v = vmap + (size_t)b * PIX_PER_B;
    const int t = threadIdx.x;
    const int y0 = t, y1 = t + 256;

    __shared__ float vs[2][H + 4];       // 2 x 516 floats, halo 2 each side
    if (t < 2) {
        vs[0][t] = 0.f; vs[0][H + 2 + t] = 0.f;
        vs[1][t] = 0.f; vs[1][H + 2 + t] = 0.f;
    }
    __syncthreads();

    float w0a = 0, w1a = 0, w2a = 0, w3a = 0, w4a = 0;
    float w0b = 0, w1b = 0, w2b = 0, w3b = 0, w4b = 0;
    float best = -1e30f;
    int bidx = 0x7fffffff;

    float a_next = 0.f, c_next = 0.f;
    {
        int gr = x0 - 2;
        if (gr >= 0) { a_next = v[gr * H + y0]; c_next = v[gr * H + y1]; }
    }

    #pragma unroll
    for (int r = 0; r < SROWS + 4; ++r) {
        float a = a_next, c = c_next;
        if (r < SROWS + 3) {                     // prefetch row r+1
            int gr = x0 - 1 + r;
            if (gr >= 0 && gr < W) {
                a_next = v[gr * H + y0];
                c_next = v[gr * H + y1];
            } else { a_next = 0.f; c_next = 0.f; }
        }
        w0a = w1a; w1a = w2a; w2a = w3a; w3a = w4a; w4a = a;
        w0b = w1b; w1b = w2b; w2b = w3b; w3b = w4b; w4b = c;

        if (r >= 4) {
            const int x = x0 + r - 4;
            const int buf = r & 1;
            vs[buf][2 + y0] = w0a + w1a + w2a + w3a + w4a;
            vs[buf][2 + y1] = w0b + w1b + w2b + w3b + w4b;
            __syncthreads();
            float sa = vs[buf][y0] + vs[buf][y0+1] + vs[buf][y0+2] + vs[buf][y0+3] + vs[buf][y0+4];
            float sb = vs[buf][y1] + vs[buf][y1+1] + vs[buf][y1+2] + vs[buf][y1+3] + vs[buf][y1+4];
            int ia = x * H + y0;
            int ib = x * H + y1;
            if (sa > best || (sa == best && ia < bidx)) { best = sa; bidx = ia; }
            if (sb > best || (sb == best && ib < bidx)) { best = sb; bidx = ib; }
        }
    }

    __shared__ float rv[256];
    __shared__ int   ri[256];
    rv[t] = best; ri[t] = bidx;
    __syncthreads();
    for (int off = 128; off; off >>= 1) {
        if (t < off) {
            float ov = rv[t + off]; int oi = ri[t + off];
            if (ov > rv[t] || (ov == rv[t] && oi < ri[t])) { rv[t] = ov; ri[t] = oi; }
        }
        __syncthreads();
    }
    if (t == 0) {
        pval[b * NSTRIPS + strip] = rv[0];
        pidx[b * NSTRIPS + strip] = ri[0];
    }
}

// ---------- K3: final per-batch reduce + output ----------
__global__ void final_kernel(const float* __restrict__ pval,
                             const int* __restrict__ pidx,
                             float* __restrict__ out) {
    int b = blockIdx.x;
    int t = threadIdx.x;  // 64 threads, first NSTRIPS valid
    float v = -1e30f;
    int idx = 0x7fffffff;
    if (t < NSTRIPS) { v = pval[b * NSTRIPS + t]; idx = pidx[b * NSTRIPS + t]; }
    #pragma unroll
    for (int off = 32; off; off >>= 1) {
        float ov = __shfl_xor(v, off, 64);
        int oi = __shfl_xor(idx, off, 64);
        if (ov > v || (ov == v && oi < idx)) { v = ov; idx = oi; }
    }
    if (t == 0) {
        out[b * 2 + 0] = (float)(idx >> 9);    // xs = flat // H
        out[b * 2 + 1] = (float)(idx & (H-1)); // ys = flat % H
        out[2 * B + b] = v;                    // max_vals after the 32 coord floats
    }
}

extern "C" void kernel_launch(void* const* d_in, const int* in_sizes, int n_in,
                              void* d_out, int out_size, void* d_ws, size_t ws_size,
                              hipStream_t stream) {
    const float* mf = (const float*)d_in[0];   // (16,512,512,64)
    const float* qf = (const float*)d_in[1];   // (16,64)
    float* out = (float*)d_out;                // 48 floats

    char* ws = (char*)d_ws;
    float* vmap = (float*)ws;                           // 16*512*512 f (16 MiB)
    char* after = ws + (size_t)NPIX * 4;
    float* pval = (float*)after;                        // 512 floats
    int*   pidx = (int*)(after + 4096);                 // 512 ints

    dim3 vgrid(GX, B);
    vmap_kernel<<<vgrid, 256, 0, stream>>>(mf, qf, vmap);
    dim3 sgrid(NSTRIPS, B);
    score_kernel<<<sgrid, 256, 0, stream>>>(vmap, pval, pidx);
    final_kernel<<<B, 64, 0, stream>>>(pval, pidx, out);
}

// Round 7
// 194.590 us; speedup vs baseline: 1.5086x; 1.0824x over previous
//
#include <hip/hip_runtime.h>
#include <hip/hip_bf16.h>

// Problem: b=16, W=512, H=512, E=64, fp32 in.
// out: 16x2 coords (written as float) then 16 max vals (float). 48 floats.

#define B 16
#define W 512
#define H 512
#define E 64
#define NPIX ((size_t)B * W * H)
#define PIX_PER_B (W * H)
#define SROWS 16          // output rows per score block
#define NSTRIPS (W / SROWS)
#define EPS 1e-8f
#define GX 128            // blocks per batch for vmap

// native clang vector type — __builtin_nontemporal_load requires this
// (HIP's float4 is a struct and is rejected)
typedef float floatx4 __attribute__((ext_vector_type(4)));

// Sum across each 16-lane DPP row via row_shl cascade; result valid in lane 0
// of each row. VALU-only (no DS pipe), bound_ctrl=1 shifts zeros in from the
// row edge. row_shl:N = 0x100|N.
__device__ __forceinline__ float row16_sum(float x) {
    int s;
    s = __builtin_amdgcn_update_dpp(0, __float_as_int(x), 0x101, 0xf, 0xf, true);
    x += __int_as_float(s);
    s = __builtin_amdgcn_update_dpp(0, __float_as_int(x), 0x102, 0xf, 0xf, true);
    x += __int_as_float(s);
    s = __builtin_amdgcn_update_dpp(0, __float_as_int(x), 0x104, 0xf, 0xf, true);
    x += __int_as_float(s);
    s = __builtin_amdgcn_update_dpp(0, __float_as_int(x), 0x108, 0xf, 0xf, true);
    x += __int_as_float(s);
    return x;
}

// ---------- K1: cosine value map (persistent, grid-stride, 4x unrolled) ----------
// 16 lanes per pixel; lane j loads 16B of embedding elems [4j..4j+3].
// Each block owns 64 CONSECUTIVE pixels (16 KB contiguous) per iteration so
// the DRAM access front is dense (page/row locality). nt loads: no cache
// allocate on the use-once 1 GB stream.
__global__ __launch_bounds__(256) void vmap_kernel(const float* __restrict__ mf,
                                                   const float* __restrict__ qf,
                                                   float* __restrict__ vmap) {
    const int b = blockIdx.y;
    const int t = threadIdx.x;
    const int j = t & 15;

    floatx4 q4 = *reinterpret_cast<const floatx4*>(qf + b * E + j * 4);
    float qs = q4.x * q4.x + q4.y * q4.y + q4.z * q4.z + q4.w * q4.w;
    #pragma unroll
    for (int off = 8; off; off >>= 1) qs += __shfl_xor(qs, off, 16);
    const float qinv = rsqrtf(qs + EPS);
    q4 *= qinv;

    const float* mfb = mf + (size_t)b * PIX_PER_B * E;
    float* vb = vmap + (size_t)b * PIX_PER_B;

    #pragma unroll 1
    for (int it = 0; it < PIX_PER_B / (GX * 64); ++it) {   // 32 iterations
        const int tile = blockIdx.x + it * GX;             // 64-pixel tile
        const int p = tile * 64 + (t >> 4);                // group's pixel in tile

        const floatx4 m0 = __builtin_nontemporal_load(
            reinterpret_cast<const floatx4*>(mfb + (size_t)(p     ) * E + j * 4));
        const floatx4 m1 = __builtin_nontemporal_load(
            reinterpret_cast<const floatx4*>(mfb + (size_t)(p + 16) * E + j * 4));
        const floatx4 m2 = __builtin_nontemporal_load(
            reinterpret_cast<const floatx4*>(mfb + (size_t)(p + 32) * E + j * 4));
        const floatx4 m3 = __builtin_nontemporal_load(
            reinterpret_cast<const floatx4*>(mfb + (size_t)(p + 48) * E + j * 4));

        float d0 = m0.x*q4.x + m0.y*q4.y + m0.z*q4.z + m0.w*q4.w;
        float s0 = m0.x*m0.x + m0.y*m0.y + m0.z*m0.z + m0.w*m0.w;
        float d1 = m1.x*q4.x + m1.y*q4.y + m1.z*q4.z + m1.w*q4.w;
        float s1 = m1.x*m1.x + m1.y*m1.y + m1.z*m1.z + m1.w*m1.w;
        float d2 = m2.x*q4.x + m2.y*q4.y + m2.z*q4.z + m2.w*q4.w;
        float s2 = m2.x*m2.x + m2.y*m2.y + m2.z*m2.z + m2.w*m2.w;
        float d3 = m3.x*q4.x + m3.y*q4.y + m3.z*q4.z + m3.w*q4.w;
        float s3 = m3.x*m3.x + m3.y*m3.y + m3.z*m3.z + m3.w*m3.w;

        d0 = row16_sum(d0);  s0 = row16_sum(s0);
        d1 = row16_sum(d1);  s1 = row16_sum(s1);
        d2 = row16_sum(d2);  s2 = row16_sum(s2);
        d3 = row16_sum(d3);  s3 = row16_sum(s3);

        if (j == 0) {
            vb[p     ] = d0 * rsqrtf(s0 + EPS);
            vb[p + 16] = d1 * rsqrtf(s1 + EPS);
            vb[p + 32] = d2 * rsqrtf(s2 + EPS);
            vb[p + 48] = d3 * rsqrtf(s3 + EPS);
        }
    }
}

// ---------- K2: 5x5 window sum + per-strip argmax (vertical-first separable) ----------
__global__ __launch_bounds__(256) void score_kernel(const float* __restrict__ vmap,
                                                    float* __restrict__ pval,
                                                    int* __restrict__ pidx) {
    const int strip = blockIdx.x;
    const int b = blockIdx.y;
    const int x0 = strip * SROWS;
    const float* v = vmap + (size_t)b * PIX_PER_B;
    const int t = threadIdx.x;
    const int y0 = t, y1 = t + 256;

    __shared__ float vs[2][H + 4];       // 2 x 516 floats, halo 2 each side
    if (t < 2) {
        vs[0][t] = 0.f; vs[0][H + 2 + t] = 0.f;
        vs[1][t] = 0.f; vs[1][H + 2 + t] = 0.f;
    }
    __syncthreads();

    float w0a = 0, w1a = 0, w2a = 0, w3a = 0, w4a = 0;
    float w0b = 0, w1b = 0, w2b = 0, w3b = 0, w4b = 0;
    float best = -1e30f;
    int bidx = 0x7fffffff;

    float a_next = 0.f, c_next = 0.f;
    {
        int gr = x0 - 2;
        if (gr >= 0) { a_next = v[gr * H + y0]; c_next = v[gr * H + y1]; }
    }

    #pragma unroll
    for (int r = 0; r < SROWS + 4; ++r) {
        float a = a_next, c = c_next;
        if (r < SROWS + 3) {                     // prefetch row r+1
            int gr = x0 - 1 + r;
            if (gr >= 0 && gr < W) {
                a_next = v[gr * H + y0];
                c_next = v[gr * H + y1];
            } else { a_next = 0.f; c_next = 0.f; }
        }
        w0a = w1a; w1a = w2a; w2a = w3a; w3a = w4a; w4a = a;
        w0b = w1b; w1b = w2b; w2b = w3b; w3b = w4b; w4b = c;

        if (r >= 4) {
            const int x = x0 + r - 4;
            const int buf = r & 1;
            vs[buf][2 + y0] = w0a + w1a + w2a + w3a + w4a;
            vs[buf][2 + y1] = w0b + w1b + w2b + w3b + w4b;
            __syncthreads();
            float sa = vs[buf][y0] + vs[buf][y0+1] + vs[buf][y0+2] + vs[buf][y0+3] + vs[buf][y0+4];
            float sb = vs[buf][y1] + vs[buf][y1+1] + vs[buf][y1+2] + vs[buf][y1+3] + vs[buf][y1+4];
            int ia = x * H + y0;
            int ib = x * H + y1;
            if (sa > best || (sa == best && ia < bidx)) { best = sa; bidx = ia; }
            if (sb > best || (sb == best && ib < bidx)) { best = sb; bidx = ib; }
        }
    }

    __shared__ float rv[256];
    __shared__ int   ri[256];
    rv[t] = best; ri[t] = bidx;
    __syncthreads();
    for (int off = 128; off; off >>= 1) {
        if (t < off) {
            float ov = rv[t + off]; int oi = ri[t + off];
            if (ov > rv[t] || (ov == rv[t] && oi < ri[t])) { rv[t] = ov; ri[t] = oi; }
        }
        __syncthreads();
    }
    if (t == 0) {
        pval[b * NSTRIPS + strip] = rv[0];
        pidx[b * NSTRIPS + strip] = ri[0];
    }
}

// ---------- K3: final per-batch reduce + output ----------
__global__ void final_kernel(const float* __restrict__ pval,
                             const int* __restrict__ pidx,
                             float* __restrict__ out) {
    int b = blockIdx.x;
    int t = threadIdx.x;  // 64 threads, first NSTRIPS valid
    float v = -1e30f;
    int idx = 0x7fffffff;
    if (t < NSTRIPS) { v = pval[b * NSTRIPS + t]; idx = pidx[b * NSTRIPS + t]; }
    #pragma unroll
    for (int off = 32; off; off >>= 1) {
        float ov = __shfl_xor(v, off, 64);
        int oi = __shfl_xor(idx, off, 64);
        if (ov > v || (ov == v && oi < idx)) { v = ov; idx = oi; }
    }
    if (t == 0) {
        out[b * 2 + 0] = (float)(idx >> 9);    // xs = flat // H
        out[b * 2 + 1] = (float)(idx & (H-1)); // ys = flat % H
        out[2 * B + b] = v;                    // max_vals after the 32 coord floats
    }
}

extern "C" void kernel_launch(void* const* d_in, const int* in_sizes, int n_in,
                              void* d_out, int out_size, void* d_ws, size_t ws_size,
                              hipStream_t stream) {
    const float* mf = (const float*)d_in[0];   // (16,512,512,64)
    const float* qf = (const float*)d_in[1];   // (16,64)
    float* out = (float*)d_out;                // 48 floats

    char* ws = (char*)d_ws;
    float* vmap = (float*)ws;                           // 16*512*512 f (16 MiB)
    char* after = ws + (size_t)NPIX * 4;
    float* pval = (float*)after;                        // 512 floats
    int*   pidx = (int*)(after + 4096);                 // 512 ints

    dim3 vgrid(GX, B);
    vmap_kernel<<<vgrid, 256, 0, stream>>>(mf, qf, vmap);
    dim3 sgrid(NSTRIPS, B);
    score_kernel<<<sgrid, 256, 0, stream>>>(vmap, pval, pidx);
    final_kernel<<<B, 64, 0, stream>>>(pval, pidx, out);
}